// Round 3
// baseline (215.672 us; speedup 1.0000x reference)
//
#include <hip/hip_runtime.h>
#include <hip/hip_bf16.h>

typedef short short8 __attribute__((ext_vector_type(8)));
typedef float f32x4 __attribute__((ext_vector_type(4)));
typedef unsigned int uint;

#define CB   16
#define TT   8
#define CIN  1024
#define ICH  512
#define HWS  196
#define NPB  1568   // cols per batch (196*8)
#define NF   25088  // flat cols = 16*1568 = 196*128 exactly
#define RT_N 196    // 128-tiles over NF

static __device__ __forceinline__ float bf2f(unsigned short u) {
  uint t = ((uint)u) << 16; float f; __builtin_memcpy(&f, &t, 4); return f;
}
static __device__ __forceinline__ unsigned short f2bf(float f) {
  __hip_bfloat16 h = __float2bfloat16(f); unsigned short u; __builtin_memcpy(&u, &h, 2); return u;
}

// async global->LDS, 16B per lane; LDS dest is wave-uniform base + lane*16
static __device__ __forceinline__ void stage16(const void* g, void* l) {
  __builtin_amdgcn_global_load_lds(
      (const __attribute__((address_space(1))) unsigned int*)(unsigned long long)g,
      (__attribute__((address_space(3))) unsigned int*)(unsigned int)(unsigned long long)l,
      16, 0, 0);
}

// ---------------- prep: weights -> bf16, fold 4 depthwise convs into one 7-tap ----------------
__global__ void k_prep_weights(const float* __restrict__ w1, const float* __restrict__ w2,
    const float* __restrict__ wb1, const float* __restrict__ bb1,
    const float* __restrict__ wb2, const float* __restrict__ bb2,
    const float* __restrict__ wb3, const float* __restrict__ bb3,
    const float* __restrict__ wb4, const float* __restrict__ bb4,
    __hip_bfloat16* __restrict__ w1b, __hip_bfloat16* __restrict__ w2b,
    float* __restrict__ weff, float* __restrict__ beff) {
  int idx = blockIdx.x * 256 + threadIdx.x;
  if (idx < CIN * ICH) {
    w1b[idx] = __float2bfloat16(w1[idx]);
    w2b[idx] = __float2bfloat16(w2[idx]);
  }
  if (idx < ICH) {
    float e[7];
#pragma unroll
    for (int u = 0; u < 7; u++) e[u] = wb4[idx * 7 + u];
#pragma unroll
    for (int u = 0; u < 5; u++) e[u + 1] += wb3[idx * 5 + u];
#pragma unroll
    for (int u = 0; u < 3; u++) e[u + 2] += wb2[idx * 3 + u];
    e[3] += wb1[idx];
#pragma unroll
    for (int u = 0; u < 7; u++) weff[idx * 8 + u] = e[u];
    weff[idx * 8 + 7] = 0.f;
    beff[idx] = bb1[idx] + bb2[idx] + bb3[idx] + bb4[idx];
  }
}

// ---------------- prep: x (BT,C,HW) fp32 -> xbT[n=(b,hw,t)][c] bf16 ----------------
__global__ void k_prep_x(const float* __restrict__ x, __hip_bfloat16* __restrict__ xbT) {
  __shared__ float tile[64][51];
  int bid = blockIdx.x;
  int ht = bid & 3;          // 4 hw-tiles of 49
  int ct = (bid >> 2) & 15;  // 16 c-tiles of 64
  int t  = (bid >> 6) & 7;
  int b  = bid >> 9;
  int c0 = ct * 64, h0 = ht * 49;
  const float* src = x + ((size_t)((b * TT + t) * CIN + c0)) * HWS + h0;
  for (int idx = threadIdx.x; idx < 64 * 49; idx += 256) {
    int r = idx / 49, q = idx - r * 49;
    tile[r][q] = src[(size_t)r * HWS + q];
  }
  __syncthreads();
  for (int idx = threadIdx.x; idx < 49 * 16; idx += 256) {
    int h = idx >> 4, g = idx & 15;
    ushort4 pk;
    pk.x = f2bf(tile[g * 4 + 0][h]);
    pk.y = f2bf(tile[g * 4 + 1][h]);
    pk.z = f2bf(tile[g * 4 + 2][h]);
    pk.w = f2bf(tile[g * 4 + 3][h]);
    size_t n1 = (size_t)(h0 + h) * TT + t;
    *(ushort4*)&xbT[((size_t)b * NPB + n1) * CIN + (c0 + g * 4)] = pk;
  }
}

// ---------------- 2-phase double-buffered GEMM core: 128x128 tile, BK=32 ----------------
// One __syncthreads per K-step; stage of tile t+1 issued BEFORE compute of tile t,
// so the barrier's implicit vmcnt(0) drain overlaps with ds_read+MFMA of tile t.
template <int KD>
static __device__ __forceinline__ void gemm_core(
    const __hip_bfloat16* __restrict__ Ar,  // 128 rows x KD (k-contiguous)
    const __hip_bfloat16* __restrict__ Br,  // 128 rows x KD
    __hip_bfloat16* As, __hip_bfloat16* Bs, f32x4 (&acc)[4][4]) {
  int tid = threadIdx.x;
  int lane = tid & 63, w = tid >> 6;
  int wm = w >> 1, wn = w & 1, ln = lane & 15, lm = lane >> 4;
  int rseg = lane >> 2;        // 0..15 row within 16-row segment
  int kb = (lane & 3) * 8;     // bf16 offset within BK=32
  const __hip_bfloat16* ga0 = Ar + (size_t)(w * 32 + rseg) * KD + kb;
  const __hip_bfloat16* ga1 = ga0 + (size_t)16 * KD;
  const __hip_bfloat16* gb0 = Br + (size_t)(w * 32 + rseg) * KD + kb;
  const __hip_bfloat16* gb1 = gb0 + (size_t)16 * KD;
  __hip_bfloat16* la0 = As + w * 1024;      // +512 for second 16-row chunk
  __hip_bfloat16* lb0 = Bs + w * 1024;
  constexpr int NT = KD / 32;

  // prologue: stage tile 0 into buf 0
  stage16(ga0, la0);
  stage16(ga1, la0 + 512);
  stage16(gb0, lb0);
  stage16(gb1, lb0 + 512);
  __syncthreads();

  int cur = 0;
  int aoff[4], boff[4];
#pragma unroll
  for (int f = 0; f < 4; f++) {
    aoff[f] = (wm * 64 + f * 16 + ln) * 32 + lm * 8;
    boff[f] = (wn * 64 + f * 16 + ln) * 32 + lm * 8;
  }

  for (int t = 0; t < NT - 1; t++) {
    int nb = cur ^ 1;
    int k1 = (t + 1) * 32;
    stage16(ga0 + k1, la0 + nb * 4096);
    stage16(ga1 + k1, la0 + nb * 4096 + 512);
    stage16(gb0 + k1, lb0 + nb * 4096);
    stage16(gb1 + k1, lb0 + nb * 4096 + 512);
    short8 af[4], bf[4];
#pragma unroll
    for (int mf = 0; mf < 4; mf++) af[mf] = *(const short8*)&As[cur * 4096 + aoff[mf]];
#pragma unroll
    for (int nf = 0; nf < 4; nf++) bf[nf] = *(const short8*)&Bs[cur * 4096 + boff[nf]];
    __builtin_amdgcn_s_setprio(1);
#pragma unroll
    for (int mf = 0; mf < 4; mf++)
#pragma unroll
      for (int nf = 0; nf < 4; nf++)
        acc[mf][nf] = __builtin_amdgcn_mfma_f32_16x16x32_bf16(af[mf], bf[nf], acc[mf][nf], 0, 0, 0);
    __builtin_amdgcn_s_setprio(0);
    __syncthreads();  // vmcnt(0)+lgkmcnt(0) drain: next buf ready, this buf free
    cur = nb;
  }
  // last tile
  short8 af[4], bf[4];
#pragma unroll
  for (int mf = 0; mf < 4; mf++) af[mf] = *(const short8*)&As[cur * 4096 + aoff[mf]];
#pragma unroll
  for (int nf = 0; nf < 4; nf++) bf[nf] = *(const short8*)&Bs[cur * 4096 + boff[nf]];
  __builtin_amdgcn_s_setprio(1);
#pragma unroll
  for (int mf = 0; mf < 4; mf++)
#pragma unroll
    for (int nf = 0; nf < 4; nf++)
      acc[mf][nf] = __builtin_amdgcn_mfma_f32_16x16x32_bf16(af[mf], bf[nf], acc[mf][nf], 0, 0, 0);
  __builtin_amdgcn_s_setprio(0);
}

// ---------------- GEMM1: zT[n][o] = xbT[n][:] . w1b[o][:] + b1[o], bf16 out ----------------
__global__ __launch_bounds__(256) void k_gemm1(const __hip_bfloat16* __restrict__ xbT,
                                               const __hip_bfloat16* __restrict__ w1b,
                                               const float* __restrict__ b1,
                                               __hip_bfloat16* __restrict__ zb) {
  __shared__ __hip_bfloat16 As[2 * 128 * 32], Bs[2 * 128 * 32];
  // bijective XCD swizzle: nwg=784, 98 per XCD; consecutive swz share n-panel
  int swz = (blockIdx.x & 7) * 98 + (blockIdx.x >> 3);
  int rt = swz >> 2, ot = swz & 3;
  int n0 = rt * 128, o0 = ot * 128;
  f32x4 acc[4][4];
#pragma unroll
  for (int a = 0; a < 4; a++)
#pragma unroll
    for (int c = 0; c < 4; c++) acc[a][c] = (f32x4){0.f, 0.f, 0.f, 0.f};
  gemm_core<1024>(xbT + (size_t)n0 * CIN, w1b + (size_t)o0 * CIN, As, Bs, acc);
  int tid = threadIdx.x, lane = tid & 63, w = tid >> 6;
  int wm = w >> 1, wn = w & 1, ln = lane & 15, lm = lane >> 4;
#pragma unroll
  for (int nf = 0; nf < 4; nf++) {
    int o = o0 + wn * 64 + nf * 16 + ln;
    float bo = b1[o];
#pragma unroll
    for (int mf = 0; mf < 4; mf++) {
      int nr = n0 + wm * 64 + mf * 16 + lm * 4;
#pragma unroll
      for (int j = 0; j < 4; j++)
        zb[(size_t)(nr + j) * ICH + o] = __float2bfloat16(acc[mf][nf][j] + bo);
    }
  }
}

// ---------------- conv: zb[n][o] -> dwT[n2=(b, t*196+hw)][o], 7-tap along t ----------------
__global__ void k_conv(const __hip_bfloat16* __restrict__ zb, const float* __restrict__ weff,
                       const float* __restrict__ beff, __hip_bfloat16* __restrict__ dwT) {
  int bid = blockIdx.x;  // b*HWS + hw
  int hw = bid % HWS, b = bid / HWS;
  int o = threadIdx.x * 2;
  size_t nb = (size_t)b * NPB + hw * TT;
  float z0[TT], z1[TT];
#pragma unroll
  for (int t = 0; t < TT; t++) {
    uint v = *(const uint*)&zb[(nb + t) * ICH + o];
    z0[t] = bf2f((unsigned short)(v & 0xffff));
    z1[t] = bf2f((unsigned short)(v >> 16));
  }
  float e0[7], e1[7];
#pragma unroll
  for (int u = 0; u < 7; u++) { e0[u] = weff[o * 8 + u]; e1[u] = weff[(o + 1) * 8 + u]; }
  float be0 = beff[o], be1 = beff[o + 1];
#pragma unroll
  for (int t = 0; t < TT; t++) {
    float s0 = be0, s1 = be1;
#pragma unroll
    for (int u = 0; u < 7; u++) {
      int tt = t + u - 3;
      if (tt >= 0 && tt < TT) { s0 += e0[u] * z0[tt]; s1 += e1[u] * z1[tt]; }
    }
    uint pk = ((uint)f2bf(s1) << 16) | f2bf(s0);
    *(uint*)&dwT[((size_t)b * NPB + t * HWS + hw) * ICH + o] = pk;
  }
}

// ---------------- GEMM2: out[o2][n2] = w2b[o2][:] . dwT[n2][:] + b2 + residual ----------------
__global__ __launch_bounds__(256) void k_gemm2(const __hip_bfloat16* __restrict__ dwT,
                                               const __hip_bfloat16* __restrict__ w2b,
                                               const float* __restrict__ b2,
                                               const float* __restrict__ xres,
                                               float* __restrict__ out) {
  __shared__ __hip_bfloat16 As[2 * 128 * 32], Bs[2 * 128 * 32];
  // bijective XCD swizzle: nwg=1568, 196 per XCD; consecutive swz share n-panel
  int swz = (blockIdx.x & 7) * 196 + (blockIdx.x >> 3);
  int nt = swz >> 3, mt = swz & 7;
  int n0 = nt * 128, m0 = mt * 128;
  f32x4 acc[4][4];
#pragma unroll
  for (int a = 0; a < 4; a++)
#pragma unroll
    for (int c = 0; c < 4; c++) acc[a][c] = (f32x4){0.f, 0.f, 0.f, 0.f};
  gemm_core<512>(w2b + (size_t)m0 * ICH, dwT + (size_t)n0 * ICH, As, Bs, acc);
  int tid = threadIdx.x, lane = tid & 63, w = tid >> 6;
  int wm = w >> 1, wn = w & 1, ln = lane & 15, lm = lane >> 4;
#pragma unroll
  for (int nf = 0; nf < 4; nf++) {
    int n2f = n0 + wn * 64 + nf * 16 + ln;
    int b = n2f / NPB;
    int r = n2f - b * NPB;
    int t = r / HWS;
    int hw = r - t * HWS;
    size_t colbase = (size_t)((b * TT + t) * CIN) * HWS + hw;
#pragma unroll
    for (int mf = 0; mf < 4; mf++) {
      int o2b = m0 + wm * 64 + mf * 16 + lm * 4;
#pragma unroll
      for (int j = 0; j < 4; j++) {
        int o2 = o2b + j;
        size_t a = colbase + (size_t)o2 * HWS;
        out[a] = acc[mf][nf][j] + b2[o2] + xres[a];
      }
    }
  }
}

extern "C" void kernel_launch(void* const* d_in, const int* in_sizes, int n_in,
                              void* d_out, int out_size, void* d_ws, size_t ws_size,
                              hipStream_t stream) {
  const float* x   = (const float*)d_in[0];
  const float* w1  = (const float*)d_in[1];
  const float* b1  = (const float*)d_in[2];
  const float* wb1 = (const float*)d_in[3];
  const float* bb1 = (const float*)d_in[4];
  const float* wb2 = (const float*)d_in[5];
  const float* bb2 = (const float*)d_in[6];
  const float* wb3 = (const float*)d_in[7];
  const float* bb3 = (const float*)d_in[8];
  const float* wb4 = (const float*)d_in[9];
  const float* bb4 = (const float*)d_in[10];
  const float* w2  = (const float*)d_in[11];
  const float* b2  = (const float*)d_in[12];
  float* out = (float*)d_out;

  // d_out as scratch (102.76MB total):
  //   bytes [0, 25.69M):        zb  bf16 [NF][ICH]   (dead after k_conv)
  //   bytes [51.38M, 102.76M):  xbT bf16 [NF][CIN]   (dead after k_gemm1)
  __hip_bfloat16* zb  = (__hip_bfloat16*)d_out;
  __hip_bfloat16* xbT = (__hip_bfloat16*)((char*)d_out + 51380224);

  // ws: dwT 25.69MB + w1b 1MB + w2b 1MB + weff 16KB + beff 2KB  (~27.7MB)
  char* ws = (char*)d_ws;
  __hip_bfloat16* dwT = (__hip_bfloat16*)ws;
  __hip_bfloat16* w1b = (__hip_bfloat16*)(ws + 25690112);
  __hip_bfloat16* w2b = (__hip_bfloat16*)(ws + 25690112 + 1048576);
  float* weff = (float*)(ws + 25690112 + 2097152);
  float* beff = weff + 4096;

  k_prep_weights<<<(CIN * ICH + 255) / 256, 256, 0, stream>>>(
      w1, w2, wb1, bb1, wb2, bb2, wb3, bb3, wb4, bb4, w1b, w2b, weff, beff);
  k_prep_x<<<CB * TT * 16 * 4, 256, 0, stream>>>(x, xbT);
  k_gemm1<<<784, 256, 0, stream>>>(xbT, w1b, b1, zb);
  k_conv<<<CB * HWS, 256, 0, stream>>>(zb, weff, beff, dwT);
  k_gemm2<<<1568, 256, 0, stream>>>(dwT, w2b, b2, x, out);
}

// Round 4
// 174.695 us; speedup vs baseline: 1.2346x; 1.2346x over previous
//
#include <hip/hip_runtime.h>
#include <hip/hip_bf16.h>

typedef short short8 __attribute__((ext_vector_type(8)));
typedef float f32x4 __attribute__((ext_vector_type(4)));
typedef unsigned int uint;

#define CB   16
#define TT   8
#define CIN  1024
#define ICH  512
#define HWS  196
#define NPB  1568   // cols per batch (196*8)
#define NF   25088  // flat cols = 16*1568

static __device__ __forceinline__ float bf2f(unsigned short u) {
  uint t = ((uint)u) << 16; float f; __builtin_memcpy(&f, &t, 4); return f;
}
static __device__ __forceinline__ unsigned short f2bf(float f) {
  __hip_bfloat16 h = __float2bfloat16(f); unsigned short u; __builtin_memcpy(&u, &h, 2); return u;
}

// async global->LDS, 16B per lane; LDS dest is wave-uniform base + lane*16
static __device__ __forceinline__ void stage16(const void* g, void* l) {
  __builtin_amdgcn_global_load_lds(
      (const __attribute__((address_space(1))) unsigned int*)(unsigned long long)g,
      (__attribute__((address_space(3))) unsigned int*)(unsigned int)(unsigned long long)l,
      16, 0, 0);
}

// ---------------- prep: weights -> bf16, fold 4 depthwise convs into one 7-tap ----------------
__global__ void k_prep_weights(const float* __restrict__ w1, const float* __restrict__ w2,
    const float* __restrict__ wb1, const float* __restrict__ bb1,
    const float* __restrict__ wb2, const float* __restrict__ bb2,
    const float* __restrict__ wb3, const float* __restrict__ bb3,
    const float* __restrict__ wb4, const float* __restrict__ bb4,
    __hip_bfloat16* __restrict__ w1b, __hip_bfloat16* __restrict__ w2b,
    float* __restrict__ weff, float* __restrict__ beff) {
  int idx = blockIdx.x * 256 + threadIdx.x;
  if (idx < CIN * ICH) {
    w1b[idx] = __float2bfloat16(w1[idx]);
    w2b[idx] = __float2bfloat16(w2[idx]);
  }
  if (idx < ICH) {
    float e[7];
#pragma unroll
    for (int u = 0; u < 7; u++) e[u] = wb4[idx * 7 + u];
#pragma unroll
    for (int u = 0; u < 5; u++) e[u + 1] += wb3[idx * 5 + u];
#pragma unroll
    for (int u = 0; u < 3; u++) e[u + 2] += wb2[idx * 3 + u];
    e[3] += wb1[idx];
#pragma unroll
    for (int u = 0; u < 7; u++) weff[idx * 8 + u] = e[u];
    weff[idx * 8 + 7] = 0.f;
    beff[idx] = bb1[idx] + bb2[idx] + bb3[idx] + bb4[idx];
  }
}

// ---------------- prep: x (BT,C,HW) fp32 -> xbT[n=(b,hw,t)][c] bf16 ----------------
__global__ void k_prep_x(const float* __restrict__ x, __hip_bfloat16* __restrict__ xbT) {
  __shared__ float tile[64][51];
  int bid = blockIdx.x;
  int ht = bid & 3;          // 4 hw-tiles of 49
  int ct = (bid >> 2) & 15;  // 16 c-tiles of 64
  int t  = (bid >> 6) & 7;
  int b  = bid >> 9;
  int c0 = ct * 64, h0 = ht * 49;
  const float* src = x + ((size_t)((b * TT + t) * CIN + c0)) * HWS + h0;
  for (int idx = threadIdx.x; idx < 64 * 49; idx += 256) {
    int r = idx / 49, q = idx - r * 49;
    tile[r][q] = src[(size_t)r * HWS + q];
  }
  __syncthreads();
  for (int idx = threadIdx.x; idx < 49 * 16; idx += 256) {
    int h = idx >> 4, g = idx & 15;
    ushort4 pk;
    pk.x = f2bf(tile[g * 4 + 0][h]);
    pk.y = f2bf(tile[g * 4 + 1][h]);
    pk.z = f2bf(tile[g * 4 + 2][h]);
    pk.w = f2bf(tile[g * 4 + 3][h]);
    size_t n1 = (size_t)(h0 + h) * TT + t;
    *(ushort4*)&xbT[((size_t)b * NPB + n1) * CIN + (c0 + g * 4)] = pk;
  }
}

// ---------------- GEMM core: 256x128 tile, BK=32, 3-buffer counted-vmcnt pipeline ----------------
// 512 threads = 8 waves (4m x 2n), per-wave 64x64 output.
// Per iter per wave: 3 stage16 (2 A-chunks + 1 B-chunk). Steady state 9 loads in
// flight; vmcnt(6) drains exactly tile t's 3 loads (issued 2 iterations earlier).
// Two raw s_barriers/iter: (1) after vmcnt wait -> tile t visible to all waves;
// (2) after lgkmcnt(0) -> all ds_reads of buf t done before it is restaged.
template <int KD>
static __device__ __forceinline__ void gemm_core(
    const __hip_bfloat16* __restrict__ Ar,  // 256 rows x KD (k-contiguous)
    const __hip_bfloat16* __restrict__ Br,  // 128 rows x KD
    __hip_bfloat16* As, __hip_bfloat16* Bs, f32x4 (&acc)[4][4]) {
  constexpr int NT = KD / 32;
  int tid = threadIdx.x;
  int lane = tid & 63, w = tid >> 6;   // w 0..7
  int wm = w >> 1, wn = w & 1;
  int ln = lane & 15, lm = lane >> 4;
  int rseg = lane >> 2;        // 0..15 row within 16-row chunk
  int kb = (lane & 3) * 8;     // bf16 offset within BK=32
  const __hip_bfloat16* ga0 = Ar + (size_t)(w * 32 + rseg) * KD + kb;
  const __hip_bfloat16* ga1 = ga0 + (size_t)16 * KD;
  const __hip_bfloat16* gb0 = Br + (size_t)(w * 16 + rseg) * KD + kb;
  __hip_bfloat16* la = As + w * 1024;  // wave's A slot (32 rows x 32k); buf stride 8192 elems
  __hip_bfloat16* lb = Bs + w * 512;   // wave's B slot (16 rows x 32k); buf stride 4096 elems

  // prologue: tiles 0,1 into bufs 0,1
  stage16(ga0, la);
  stage16(ga1, la + 512);
  stage16(gb0, lb);
  stage16(ga0 + 32, la + 8192);
  stage16(ga1 + 32, la + 8192 + 512);
  stage16(gb0 + 32, lb + 4096);

  int aoff[4], boff[4];
#pragma unroll
  for (int f = 0; f < 4; f++) {
    aoff[f] = (wm * 64 + f * 16 + ln) * 32 + lm * 8;
    boff[f] = (wn * 64 + f * 16 + ln) * 32 + lm * 8;
  }

  for (int t = 0; t < NT; t++) {
    if (t + 2 < NT) {
      int bs = (t + 2) % 3;
      int k2 = (t + 2) * 32;
      stage16(ga0 + k2, la + bs * 8192);
      stage16(ga1 + k2, la + bs * 8192 + 512);
      stage16(gb0 + k2, lb + bs * 4096);
    }
    if (t + 2 < NT)      asm volatile("s_waitcnt vmcnt(6)" ::: "memory");
    else if (t + 1 < NT) asm volatile("s_waitcnt vmcnt(3)" ::: "memory");
    else                 asm volatile("s_waitcnt vmcnt(0)" ::: "memory");
    asm volatile("s_barrier" ::: "memory");  // tile t fully in LDS for all waves
    int bc = t % 3;
    short8 af[4], bf[4];
#pragma unroll
    for (int mf = 0; mf < 4; mf++) af[mf] = *(const short8*)&As[bc * 8192 + aoff[mf]];
#pragma unroll
    for (int nf = 0; nf < 4; nf++) bf[nf] = *(const short8*)&Bs[bc * 4096 + boff[nf]];
    asm volatile("s_waitcnt lgkmcnt(0)" ::: "memory");
    __builtin_amdgcn_sched_barrier(0);       // rule #18: keep MFMA below the lgkm wait
    asm volatile("s_barrier" ::: "memory");  // buf t free for restage next iter
    __builtin_amdgcn_s_setprio(1);
#pragma unroll
    for (int mf = 0; mf < 4; mf++)
#pragma unroll
      for (int nf = 0; nf < 4; nf++)
        acc[mf][nf] = __builtin_amdgcn_mfma_f32_16x16x32_bf16(af[mf], bf[nf], acc[mf][nf], 0, 0, 0);
    __builtin_amdgcn_s_setprio(0);
  }
}

// ---------------- GEMM1: zb[n][o] = xbT[n][:] . w1b[o][:] + b1[o], bf16 out ----------------
__global__ __launch_bounds__(512, 4) void k_gemm1(const __hip_bfloat16* __restrict__ xbT,
                                                  const __hip_bfloat16* __restrict__ w1b,
                                                  const float* __restrict__ b1,
                                                  __hip_bfloat16* __restrict__ zb) {
  __shared__ __hip_bfloat16 As[3 * 256 * 32];
  __shared__ __hip_bfloat16 Bs[3 * 128 * 32];
  // 392 blocks; bijective XCD swizzle, o-tile fastest within XCD
  int swz = (blockIdx.x & 7) * 49 + (blockIdx.x >> 3);
  int rt = swz >> 2, ot = swz & 3;
  int n0 = rt * 256, o0 = ot * 128;
  f32x4 acc[4][4];
#pragma unroll
  for (int a = 0; a < 4; a++)
#pragma unroll
    for (int c = 0; c < 4; c++) acc[a][c] = (f32x4){0.f, 0.f, 0.f, 0.f};
  gemm_core<1024>(xbT + (size_t)n0 * CIN, w1b + (size_t)o0 * CIN, As, Bs, acc);
  int tid = threadIdx.x, lane = tid & 63, w = tid >> 6;
  int wm = w >> 1, wn = w & 1, ln = lane & 15, lm = lane >> 4;
#pragma unroll
  for (int nf = 0; nf < 4; nf++) {
    int o = o0 + wn * 64 + nf * 16 + ln;
    float bo = b1[o];
#pragma unroll
    for (int mf = 0; mf < 4; mf++) {
      int nr = n0 + wm * 64 + mf * 16 + lm * 4;
#pragma unroll
      for (int j = 0; j < 4; j++)
        zb[(size_t)(nr + j) * ICH + o] = __float2bfloat16(acc[mf][nf][j] + bo);
    }
  }
}

// ---------------- conv: zb[n][o] -> dwT[n2=(b, t*196+hw)][o], 7-tap along t ----------------
__global__ void k_conv(const __hip_bfloat16* __restrict__ zb, const float* __restrict__ weff,
                       const float* __restrict__ beff, __hip_bfloat16* __restrict__ dwT) {
  int bid = blockIdx.x;  // b*HWS + hw
  int hw = bid % HWS, b = bid / HWS;
  int o = threadIdx.x * 2;
  size_t nb = (size_t)b * NPB + hw * TT;
  float z0[TT], z1[TT];
#pragma unroll
  for (int t = 0; t < TT; t++) {
    uint v = *(const uint*)&zb[(nb + t) * ICH + o];
    z0[t] = bf2f((unsigned short)(v & 0xffff));
    z1[t] = bf2f((unsigned short)(v >> 16));
  }
  float e0[7], e1[7];
#pragma unroll
  for (int u = 0; u < 7; u++) { e0[u] = weff[o * 8 + u]; e1[u] = weff[(o + 1) * 8 + u]; }
  float be0 = beff[o], be1 = beff[o + 1];
#pragma unroll
  for (int t = 0; t < TT; t++) {
    float s0 = be0, s1 = be1;
#pragma unroll
    for (int u = 0; u < 7; u++) {
      int tt = t + u - 3;
      if (tt >= 0 && tt < TT) { s0 += e0[u] * z0[tt]; s1 += e1[u] * z1[tt]; }
    }
    uint pk = ((uint)f2bf(s1) << 16) | f2bf(s0);
    *(uint*)&dwT[((size_t)b * NPB + t * HWS + hw) * ICH + o] = pk;
  }
}

// ---------------- GEMM2: out[o2][n2] = w2b[o2][:] . dwT[n2][:] + b2 + residual ----------------
__global__ __launch_bounds__(512, 4) void k_gemm2(const __hip_bfloat16* __restrict__ dwT,
                                                  const __hip_bfloat16* __restrict__ w2b,
                                                  const float* __restrict__ b2,
                                                  const float* __restrict__ xres,
                                                  float* __restrict__ out) {
  __shared__ __hip_bfloat16 As[3 * 256 * 32];
  __shared__ __hip_bfloat16 Bs[3 * 128 * 32];
  // 784 blocks; bijective XCD swizzle, m-tile fastest within XCD
  int swz = (blockIdx.x & 7) * 98 + (blockIdx.x >> 3);
  int nt = swz >> 2, mt = swz & 3;
  int n0 = nt * 128, m0 = mt * 256;
  f32x4 acc[4][4];
#pragma unroll
  for (int a = 0; a < 4; a++)
#pragma unroll
    for (int c = 0; c < 4; c++) acc[a][c] = (f32x4){0.f, 0.f, 0.f, 0.f};
  gemm_core<512>(w2b + (size_t)m0 * ICH, dwT + (size_t)n0 * ICH, As, Bs, acc);
  int tid = threadIdx.x, lane = tid & 63, w = tid >> 6;
  int wm = w >> 1, wn = w & 1, ln = lane & 15, lm = lane >> 4;
#pragma unroll
  for (int nf = 0; nf < 4; nf++) {
    int n2f = n0 + wn * 64 + nf * 16 + ln;
    int b = n2f / NPB;
    int r = n2f - b * NPB;
    int t = r / HWS;
    int hw = r - t * HWS;
    size_t colbase = (size_t)((b * TT + t) * CIN) * HWS + hw;
#pragma unroll
    for (int mf = 0; mf < 4; mf++) {
      int o2b = m0 + wm * 64 + mf * 16 + lm * 4;
#pragma unroll
      for (int j = 0; j < 4; j++) {
        int o2 = o2b + j;
        size_t a = colbase + (size_t)o2 * HWS;
        out[a] = acc[mf][nf][j] + b2[o2] + xres[a];
      }
    }
  }
}

extern "C" void kernel_launch(void* const* d_in, const int* in_sizes, int n_in,
                              void* d_out, int out_size, void* d_ws, size_t ws_size,
                              hipStream_t stream) {
  const float* x   = (const float*)d_in[0];
  const float* w1  = (const float*)d_in[1];
  const float* b1  = (const float*)d_in[2];
  const float* wb1 = (const float*)d_in[3];
  const float* bb1 = (const float*)d_in[4];
  const float* wb2 = (const float*)d_in[5];
  const float* bb2 = (const float*)d_in[6];
  const float* wb3 = (const float*)d_in[7];
  const float* bb3 = (const float*)d_in[8];
  const float* wb4 = (const float*)d_in[9];
  const float* bb4 = (const float*)d_in[10];
  const float* w2  = (const float*)d_in[11];
  const float* b2  = (const float*)d_in[12];
  float* out = (float*)d_out;

  // d_out as scratch (102.76MB total):
  //   bytes [0, 25.69M):        zb  bf16 [NF][ICH]   (dead after k_conv)
  //   bytes [51.38M, 102.76M):  xbT bf16 [NF][CIN]   (dead after k_gemm1)
  __hip_bfloat16* zb  = (__hip_bfloat16*)d_out;
  __hip_bfloat16* xbT = (__hip_bfloat16*)((char*)d_out + 51380224);

  // ws: dwT 25.69MB + w1b 1MB + w2b 1MB + weff 16KB + beff 2KB
  char* ws = (char*)d_ws;
  __hip_bfloat16* dwT = (__hip_bfloat16*)ws;
  __hip_bfloat16* w1b = (__hip_bfloat16*)(ws + 25690112);
  __hip_bfloat16* w2b = (__hip_bfloat16*)(ws + 25690112 + 1048576);
  float* weff = (float*)(ws + 25690112 + 2097152);
  float* beff = weff + 4096;

  k_prep_weights<<<(CIN * ICH + 255) / 256, 256, 0, stream>>>(
      w1, w2, wb1, bb1, wb2, bb2, wb3, bb3, wb4, bb4, w1b, w2b, weff, beff);
  k_prep_x<<<CB * TT * 16 * 4, 256, 0, stream>>>(x, xbT);
  k_gemm1<<<392, 512, 0, stream>>>(xbT, w1b, b1, zb);
  k_conv<<<CB * HWS, 256, 0, stream>>>(zb, weff, beff, dwT);
  k_gemm2<<<784, 512, 0, stream>>>(dwT, w2b, b2, x, out);
}

// Round 5
// 161.818 us; speedup vs baseline: 1.3328x; 1.0796x over previous
//
#include <hip/hip_runtime.h>
#include <hip/hip_bf16.h>

typedef short short8 __attribute__((ext_vector_type(8)));
typedef float f32x4 __attribute__((ext_vector_type(4)));
typedef unsigned int uint;

#define CB   16
#define TT   8
#define CIN  1024
#define ICH  512
#define HWS  196
#define NPB  1568   // cols per batch (196*8)
#define NF   25088  // flat cols = 16*1568

static __device__ __forceinline__ float bf2f(unsigned short u) {
  uint t = ((uint)u) << 16; float f; __builtin_memcpy(&f, &t, 4); return f;
}
static __device__ __forceinline__ unsigned short f2bf(float f) {
  __hip_bfloat16 h = __float2bfloat16(f); unsigned short u; __builtin_memcpy(&u, &h, 2); return u;
}

// async global->LDS, 16B per lane; LDS dest is wave-uniform base + lane*16
static __device__ __forceinline__ void stage16(const void* g, void* l) {
  __builtin_amdgcn_global_load_lds(
      (const __attribute__((address_space(1))) unsigned int*)(unsigned long long)g,
      (__attribute__((address_space(3))) unsigned int*)(unsigned int)(unsigned long long)l,
      16, 0, 0);
}

// ---------------- prep: weights -> bf16, fold 4 depthwise convs into one 7-tap ----------------
__global__ void k_prep_weights(const float* __restrict__ w1, const float* __restrict__ w2,
    const float* __restrict__ wb1, const float* __restrict__ bb1,
    const float* __restrict__ wb2, const float* __restrict__ bb2,
    const float* __restrict__ wb3, const float* __restrict__ bb3,
    const float* __restrict__ wb4, const float* __restrict__ bb4,
    __hip_bfloat16* __restrict__ w1b, __hip_bfloat16* __restrict__ w2b,
    float* __restrict__ weff, float* __restrict__ beff) {
  int idx = blockIdx.x * 256 + threadIdx.x;
  if (idx < CIN * ICH) {
    w1b[idx] = __float2bfloat16(w1[idx]);
    w2b[idx] = __float2bfloat16(w2[idx]);
  }
  if (idx < ICH) {
    float e[7];
#pragma unroll
    for (int u = 0; u < 7; u++) e[u] = wb4[idx * 7 + u];
#pragma unroll
    for (int u = 0; u < 5; u++) e[u + 1] += wb3[idx * 5 + u];
#pragma unroll
    for (int u = 0; u < 3; u++) e[u + 2] += wb2[idx * 3 + u];
    e[3] += wb1[idx];
#pragma unroll
    for (int u = 0; u < 7; u++) weff[idx * 8 + u] = e[u];
    weff[idx * 8 + 7] = 0.f;
    beff[idx] = bb1[idx] + bb2[idx] + bb3[idx] + bb4[idx];
  }
}

// ---------------- prep: x (BT,C,HW) fp32 -> xbT[n=(b,hw,t)][c] bf16 ----------------
__global__ void k_prep_x(const float* __restrict__ x, __hip_bfloat16* __restrict__ xbT) {
  __shared__ float tile[64][51];
  int bid = blockIdx.x;
  int ht = bid & 3;          // 4 hw-tiles of 49
  int ct = (bid >> 2) & 15;  // 16 c-tiles of 64
  int t  = (bid >> 6) & 7;
  int b  = bid >> 9;
  int c0 = ct * 64, h0 = ht * 49;
  const float* src = x + ((size_t)((b * TT + t) * CIN + c0)) * HWS + h0;
  for (int idx = threadIdx.x; idx < 64 * 49; idx += 256) {
    int r = idx / 49, q = idx - r * 49;
    tile[r][q] = src[(size_t)r * HWS + q];
  }
  __syncthreads();
  for (int idx = threadIdx.x; idx < 49 * 16; idx += 256) {
    int h = idx >> 4, g = idx & 15;
    ushort4 pk;
    pk.x = f2bf(tile[g * 4 + 0][h]);
    pk.y = f2bf(tile[g * 4 + 1][h]);
    pk.z = f2bf(tile[g * 4 + 2][h]);
    pk.w = f2bf(tile[g * 4 + 3][h]);
    size_t n1 = (size_t)(h0 + h) * TT + t;
    *(ushort4*)&xbT[((size_t)b * NPB + n1) * CIN + (c0 + g * 4)] = pk;
  }
}

// ---------------- GEMM core: 256x128 tile, BK=32, 3-buffer counted-vmcnt pipeline ----------------
template <int KD>
static __device__ __forceinline__ void gemm_core(
    const __hip_bfloat16* __restrict__ Ar,  // 256 rows x KD (k-contiguous)
    const __hip_bfloat16* __restrict__ Br,  // 128 rows x KD
    __hip_bfloat16* As, __hip_bfloat16* Bs, f32x4 (&acc)[4][4]) {
  constexpr int NT = KD / 32;
  int tid = threadIdx.x;
  int lane = tid & 63, w = tid >> 6;   // w 0..7
  int wm = w >> 1, wn = w & 1;
  int ln = lane & 15, lm = lane >> 4;
  int rseg = lane >> 2;        // 0..15 row within 16-row chunk
  int kb = (lane & 3) * 8;     // bf16 offset within BK=32
  const __hip_bfloat16* ga0 = Ar + (size_t)(w * 32 + rseg) * KD + kb;
  const __hip_bfloat16* ga1 = ga0 + (size_t)16 * KD;
  const __hip_bfloat16* gb0 = Br + (size_t)(w * 16 + rseg) * KD + kb;
  __hip_bfloat16* la = As + w * 1024;  // wave A slot (32 rows); buf stride 8192 elems
  __hip_bfloat16* lb = Bs + w * 512;   // wave B slot (16 rows); buf stride 4096 elems

  // prologue: tiles 0,1 into bufs 0,1
  stage16(ga0, la);
  stage16(ga1, la + 512);
  stage16(gb0, lb);
  stage16(ga0 + 32, la + 8192);
  stage16(ga1 + 32, la + 8192 + 512);
  stage16(gb0 + 32, lb + 4096);

  int aoff[4], boff[4];
#pragma unroll
  for (int f = 0; f < 4; f++) {
    aoff[f] = (wm * 64 + f * 16 + ln) * 32 + lm * 8;
    boff[f] = (wn * 64 + f * 16 + ln) * 32 + lm * 8;
  }

  for (int t = 0; t < NT; t++) {
    if (t + 2 < NT) {
      int bs = (t + 2) % 3;
      int k2 = (t + 2) * 32;
      stage16(ga0 + k2, la + bs * 8192);
      stage16(ga1 + k2, la + bs * 8192 + 512);
      stage16(gb0 + k2, lb + bs * 4096);
    }
    if (t + 2 < NT)      asm volatile("s_waitcnt vmcnt(6)" ::: "memory");
    else if (t + 1 < NT) asm volatile("s_waitcnt vmcnt(3)" ::: "memory");
    else                 asm volatile("s_waitcnt vmcnt(0)" ::: "memory");
    asm volatile("s_barrier" ::: "memory");  // tile t fully in LDS for all waves
    int bc = t % 3;
    short8 af[4], bf[4];
#pragma unroll
    for (int mf = 0; mf < 4; mf++) af[mf] = *(const short8*)&As[bc * 8192 + aoff[mf]];
#pragma unroll
    for (int nf = 0; nf < 4; nf++) bf[nf] = *(const short8*)&Bs[bc * 4096 + boff[nf]];
    asm volatile("s_waitcnt lgkmcnt(0)" ::: "memory");
    __builtin_amdgcn_sched_barrier(0);       // rule #18
    asm volatile("s_barrier" ::: "memory");  // buf t free for restage next iter
    __builtin_amdgcn_s_setprio(1);
#pragma unroll
    for (int mf = 0; mf < 4; mf++)
#pragma unroll
      for (int nf = 0; nf < 4; nf++)
        acc[mf][nf] = __builtin_amdgcn_mfma_f32_16x16x32_bf16(af[mf], bf[nf], acc[mf][nf], 0, 0, 0);
    __builtin_amdgcn_s_setprio(0);
  }
}

// ---------------- GEMM1 + fused 7-tap conv epilogue: writes dwT directly ----------------
// acc rows (wm side) = n (256-tile), cols (wn side) = o (128-tile).
// Within a C fragment, the 8 t-values of one hw-group sit in lane pair (l, l^16):
// t = (lm&1)*4 + j. Exchange via shfl_xor(16), then 7-tap per lane-half.
__global__ __launch_bounds__(512, 4) void k_gemm1(const __hip_bfloat16* __restrict__ xbT,
                                                  const __hip_bfloat16* __restrict__ w1b,
                                                  const float* __restrict__ b1,
                                                  const float* __restrict__ weff,
                                                  const float* __restrict__ beff,
                                                  __hip_bfloat16* __restrict__ dwT) {
  __shared__ __hip_bfloat16 As[3 * 256 * 32];
  __shared__ __hip_bfloat16 Bs[3 * 128 * 32];
  // 392 blocks; bijective XCD swizzle, o-tile fastest within XCD
  int swz = (blockIdx.x & 7) * 49 + (blockIdx.x >> 3);
  int rt = swz >> 2, ot = swz & 3;
  int n0 = rt * 256, o0 = ot * 128;
  f32x4 acc[4][4];
#pragma unroll
  for (int a = 0; a < 4; a++)
#pragma unroll
    for (int c = 0; c < 4; c++) acc[a][c] = (f32x4){0.f, 0.f, 0.f, 0.f};
  gemm_core<1024>(xbT + (size_t)n0 * CIN, w1b + (size_t)o0 * CIN, As, Bs, acc);

  int tid = threadIdx.x, lane = tid & 63, w = tid >> 6;
  int wm = w >> 1, wn = w & 1, ln = lane & 15, lm = lane >> 4;
  bool hiT = (lm & 1);
#pragma unroll
  for (int nf = 0; nf < 4; nf++) {
    int o = o0 + wn * 64 + nf * 16 + ln;
    float e[7];
#pragma unroll
    for (int u = 0; u < 7; u++) e[u] = weff[o * 8 + u];
    float be = beff[o];
    float bo = b1[o];
#pragma unroll
    for (int mf = 0; mf < 4; mf++) {
      float av[4], pv[4];
#pragma unroll
      for (int j = 0; j < 4; j++) av[j] = acc[mf][nf][j] + bo;
#pragma unroll
      for (int j = 0; j < 4; j++) pv[j] = __shfl_xor(av[j], 16, 64);
      float ov[4];
      if (hiT) {
        // my t = 4+j; t0..3 values = pv, t4..7 = av
#pragma unroll
        for (int j = 0; j < 4; j++) {
          float s = be;
#pragma unroll
          for (int u = 0; u < 7; u++) {
            int ss = 4 + j + u - 3;
            if (ss >= 0 && ss < 8) s += e[u] * (ss < 4 ? pv[ss] : av[ss - 4]);
          }
          ov[j] = s;
        }
      } else {
        // my t = j; t0..3 = av, t4..7 = pv
#pragma unroll
        for (int j = 0; j < 4; j++) {
          float s = be;
#pragma unroll
          for (int u = 0; u < 7; u++) {
            int ss = j + u - 3;
            if (ss >= 0 && ss < 8) s += e[u] * (ss < 4 ? av[ss] : pv[ss - 4]);
          }
          ov[j] = s;
        }
      }
      int grow = n0 + wm * 64 + mf * 16 + ((lm >> 1) & 1) * 8;  // group start row (mult of 8)
      int gidx = grow >> 3;                                      // = b*196 + hw
      int gb = gidx / HWS, ghw = gidx - gb * HWS;
      int tb = hiT ? 4 : 0;
#pragma unroll
      for (int j = 0; j < 4; j++) {
        size_t rr = (size_t)gb * NPB + (size_t)(tb + j) * HWS + ghw;
        dwT[rr * ICH + o] = __float2bfloat16(ov[j]);
      }
    }
  }
}

// ---------------- GEMM2: out = w2b . dwT + b2 + residual; LDS-bounced coalesced epilogue ----------------
__global__ __launch_bounds__(512, 4) void k_gemm2(const __hip_bfloat16* __restrict__ dwT,
                                                  const __hip_bfloat16* __restrict__ w2b,
                                                  const float* __restrict__ b2,
                                                  const float* __restrict__ xres,
                                                  float* __restrict__ out) {
  __shared__ __align__(16) char smem[73728];
  __hip_bfloat16* As = (__hip_bfloat16*)smem;            // 3*256*32 elems = 49152 B
  __hip_bfloat16* Bs = (__hip_bfloat16*)(smem + 49152);  // 3*128*32 elems = 24576 B
  // 784 blocks; bijective XCD swizzle, m-tile fastest within XCD
  int swz = (blockIdx.x & 7) * 98 + (blockIdx.x >> 3);
  int nt = swz >> 2, mt = swz & 3;
  int n0 = nt * 128, m0 = mt * 256;
  f32x4 acc[4][4];
#pragma unroll
  for (int a = 0; a < 4; a++)
#pragma unroll
    for (int c = 0; c < 4; c++) acc[a][c] = (f32x4){0.f, 0.f, 0.f, 0.f};
  gemm_core<512>(w2b + (size_t)m0 * ICH, dwT + (size_t)n0 * ICH, As, Bs, acc);

  int tid = threadIdx.x, lane = tid & 63, w = tid >> 6;
  int wm = w >> 1, wn = w & 1, ln = lane & 15, lm = lane >> 4;
  // epilogue: bounce acc through LDS as fp32 [o2l 128][col 132-pad], 2 passes over o2 halves
  float* arr = (float*)smem;
  int c = tid & 127;
  int o2r = tid >> 7;  // 0..3, wave-uniform
  int n2 = n0 + c;
  int bb = n2 / NPB, r = n2 - bb * NPB;
  int t2 = r / HWS, hw = r - t2 * HWS;
  size_t nbase = ((size_t)((bb * TT + t2) * CIN)) * HWS + hw;
#pragma unroll
  for (int pass = 0; pass < 2; pass++) {
    __syncthreads();
    if ((wm >> 1) == pass) {
#pragma unroll
      for (int mf = 0; mf < 4; mf++)
#pragma unroll
        for (int nf = 0; nf < 4; nf++)
#pragma unroll
          for (int j = 0; j < 4; j++) {
            int o2l = (wm & 1) * 64 + mf * 16 + lm * 4 + j;
            int col = wn * 64 + nf * 16 + ln;
            arr[o2l * 132 + col] = acc[mf][nf][j];
          }
    }
    __syncthreads();
    for (int it = 0; it < 32; it++) {
      int o2l = it * 4 + o2r;
      float v = arr[o2l * 132 + c];
      int o2 = m0 + pass * 128 + o2l;
      size_t a = nbase + (size_t)o2 * HWS;
      out[a] = v + b2[o2] + xres[a];
    }
  }
}

extern "C" void kernel_launch(void* const* d_in, const int* in_sizes, int n_in,
                              void* d_out, int out_size, void* d_ws, size_t ws_size,
                              hipStream_t stream) {
  const float* x   = (const float*)d_in[0];
  const float* w1  = (const float*)d_in[1];
  const float* b1  = (const float*)d_in[2];
  const float* wb1 = (const float*)d_in[3];
  const float* bb1 = (const float*)d_in[4];
  const float* wb2 = (const float*)d_in[5];
  const float* bb2 = (const float*)d_in[6];
  const float* wb3 = (const float*)d_in[7];
  const float* bb3 = (const float*)d_in[8];
  const float* wb4 = (const float*)d_in[9];
  const float* bb4 = (const float*)d_in[10];
  const float* w2  = (const float*)d_in[11];
  const float* b2  = (const float*)d_in[12];
  float* out = (float*)d_out;

  // d_out as scratch: xbT bf16 [NF][CIN] at offset 0 (51.4MB; dead before gemm2 writes out)
  __hip_bfloat16* xbT = (__hip_bfloat16*)d_out;

  // ws: dwT 25.69MB + w1b 1MB + w2b 1MB + weff 16KB + beff 2KB
  char* ws = (char*)d_ws;
  __hip_bfloat16* dwT = (__hip_bfloat16*)ws;
  __hip_bfloat16* w1b = (__hip_bfloat16*)(ws + 25690112);
  __hip_bfloat16* w2b = (__hip_bfloat16*)(ws + 25690112 + 1048576);
  float* weff = (float*)(ws + 25690112 + 2097152);
  float* beff = weff + 4096;

  k_prep_weights<<<(CIN * ICH + 255) / 256, 256, 0, stream>>>(
      w1, w2, wb1, bb1, wb2, bb2, wb3, bb3, wb4, bb4, w1b, w2b, weff, beff);
  k_prep_x<<<CB * TT * 16 * 4, 256, 0, stream>>>(x, xbT);
  k_gemm1<<<392, 512, 0, stream>>>(xbT, w1b, b1, weff, beff, dwT);
  k_gemm2<<<784, 512, 0, stream>>>(dwT, w2b, b2, x, out);
}

// Round 6
// 155.116 us; speedup vs baseline: 1.3904x; 1.0432x over previous
//
#include <hip/hip_runtime.h>
#include <hip/hip_bf16.h>

typedef short short8 __attribute__((ext_vector_type(8)));
typedef float f32x4 __attribute__((ext_vector_type(4)));
typedef unsigned int uint;

#define CB   16
#define TT   8
#define CIN  1024
#define ICH  512
#define HWS  196
#define NPB  1568   // cols per batch (196*8)
#define NF   25088  // flat cols = 16*1568

static __device__ __forceinline__ float bf2f(unsigned short u) {
  uint t = ((uint)u) << 16; float f; __builtin_memcpy(&f, &t, 4); return f;
}
static __device__ __forceinline__ unsigned short f2bf(float f) {
  __hip_bfloat16 h = __float2bfloat16(f); unsigned short u; __builtin_memcpy(&u, &h, 2); return u;
}

// async global->LDS, 16B per lane; LDS dest is wave-uniform base + lane*16
static __device__ __forceinline__ void stage16(const void* g, void* l) {
  __builtin_amdgcn_global_load_lds(
      (const __attribute__((address_space(1))) unsigned int*)(unsigned long long)g,
      (__attribute__((address_space(3))) unsigned int*)(unsigned int)(unsigned long long)l,
      16, 0, 0);
}

// ---------------- fused prep: x-transpose blocks [0,8192) + weight blocks [8192,10240) ----------------
__global__ void k_prep(const float* __restrict__ x, __hip_bfloat16* __restrict__ xbT,
    const float* __restrict__ w1, const float* __restrict__ w2,
    const float* __restrict__ wb1, const float* __restrict__ bb1,
    const float* __restrict__ wb2, const float* __restrict__ bb2,
    const float* __restrict__ wb3, const float* __restrict__ bb3,
    const float* __restrict__ wb4, const float* __restrict__ bb4,
    __hip_bfloat16* __restrict__ w1b, __hip_bfloat16* __restrict__ w2b,
    float* __restrict__ weff, float* __restrict__ beff) {
  int bid = blockIdx.x;
  if (bid >= CB * TT * 16 * 4) {
    int idx = (bid - CB * TT * 16 * 4) * 256 + threadIdx.x;
    if (idx < CIN * ICH) {
      w1b[idx] = __float2bfloat16(w1[idx]);
      w2b[idx] = __float2bfloat16(w2[idx]);
    }
    if (idx < ICH) {
      float e[7];
#pragma unroll
      for (int u = 0; u < 7; u++) e[u] = wb4[idx * 7 + u];
#pragma unroll
      for (int u = 0; u < 5; u++) e[u + 1] += wb3[idx * 5 + u];
#pragma unroll
      for (int u = 0; u < 3; u++) e[u + 2] += wb2[idx * 3 + u];
      e[3] += wb1[idx];
#pragma unroll
      for (int u = 0; u < 7; u++) weff[idx * 8 + u] = e[u];
      weff[idx * 8 + 7] = 0.f;
      beff[idx] = bb1[idx] + bb2[idx] + bb3[idx] + bb4[idx];
    }
    return;
  }
  __shared__ float tile[64][51];
  int ht = bid & 3;          // 4 hw-tiles of 49
  int ct = (bid >> 2) & 15;  // 16 c-tiles of 64
  int t  = (bid >> 6) & 7;
  int b  = bid >> 9;
  int c0 = ct * 64, h0 = ht * 49;
  const float* src = x + ((size_t)((b * TT + t) * CIN + c0)) * HWS + h0;
  for (int idx = threadIdx.x; idx < 64 * 49; idx += 256) {
    int r = idx / 49, q = idx - r * 49;
    tile[r][q] = src[(size_t)r * HWS + q];
  }
  __syncthreads();
  for (int idx = threadIdx.x; idx < 49 * 16; idx += 256) {
    int h = idx >> 4, g = idx & 15;
    ushort4 pk;
    pk.x = f2bf(tile[g * 4 + 0][h]);
    pk.y = f2bf(tile[g * 4 + 1][h]);
    pk.z = f2bf(tile[g * 4 + 2][h]);
    pk.w = f2bf(tile[g * 4 + 3][h]);
    size_t n1 = (size_t)(h0 + h) * TT + t;
    *(ushort4*)&xbT[((size_t)b * NPB + n1) * CIN + (c0 + g * 4)] = pk;
  }
}

// ---------------- GEMM core: 256x128 tile, BK=32, 3-buf counted-vmcnt, phase-interleaved ----------------
// LDS k-chunk XOR swizzle: slot(row, kq) holds global (row, kq ^ ((row&15)>>1 & 3)).
// Staging pre-swizzles the GLOBAL source per lane (LDS dest stays linear, as
// global_load_lds requires); reads apply the same involution.
// Per K-step: stage(t+2); vmcnt(6); barrier; issue 8 ds_reads (pinned order);
// then 4 MFMA-quads gated by counted lgkmcnt(3/2/1/0); barrier after lgkm(0);
// last quad slides past the barrier (register-only) to overlap next staging.
template <int KD>
static __device__ __forceinline__ void gemm_core(
    const __hip_bfloat16* __restrict__ Ar,  // 256 rows x KD (k-contiguous)
    const __hip_bfloat16* __restrict__ Br,  // 128 rows x KD
    __hip_bfloat16* As, __hip_bfloat16* Bs, f32x4 (&acc)[4][4]) {
  constexpr int NT = KD / 32;
  int tid = threadIdx.x;
  int lane = tid & 63, w = tid >> 6;   // w 0..7
  int wm = w >> 1, wn = w & 1;
  int ln = lane & 15, lm = lane >> 4;
  int rseg = lane >> 2;        // 0..15 row within 16-row chunk
  int kq  = lane & 3;
  int kb  = (kq ^ ((rseg >> 1) & 3)) * 8;  // swizzled global k-offset (bf16 elems)
  const __hip_bfloat16* ga0 = Ar + (size_t)(w * 32 + rseg) * KD + kb;
  const __hip_bfloat16* ga1 = ga0 + (size_t)16 * KD;
  const __hip_bfloat16* gb0 = Br + (size_t)(w * 16 + rseg) * KD + kb;
  __hip_bfloat16* la = As + w * 1024;  // wave A slot (32 rows); buf stride 8192 elems
  __hip_bfloat16* lb = Bs + w * 512;   // wave B slot (16 rows); buf stride 4096 elems

  // prologue: tiles 0,1 into bufs 0,1
  stage16(ga0, la);
  stage16(ga1, la + 512);
  stage16(gb0, lb);
  stage16(ga0 + 32, la + 8192);
  stage16(ga1 + 32, la + 8192 + 512);
  stage16(gb0 + 32, lb + 4096);

  int ksw = (lm ^ ((ln >> 1) & 3)) * 8;    // swizzled k-offset on the read side
  int aoff[4], boff[4];
#pragma unroll
  for (int f = 0; f < 4; f++) {
    aoff[f] = (wm * 64 + f * 16 + ln) * 32 + ksw;
    boff[f] = (wn * 64 + f * 16 + ln) * 32 + ksw;
  }

  for (int t = 0; t < NT; t++) {
    if (t + 2 < NT) {
      int bs = (t + 2) % 3;
      int k2 = (t + 2) * 32;
      stage16(ga0 + k2, la + bs * 8192);
      stage16(ga1 + k2, la + bs * 8192 + 512);
      stage16(gb0 + k2, lb + bs * 4096);
    }
    if (t + 2 < NT)      asm volatile("s_waitcnt vmcnt(6)" ::: "memory");
    else if (t + 1 < NT) asm volatile("s_waitcnt vmcnt(3)" ::: "memory");
    else                 asm volatile("s_waitcnt vmcnt(0)" ::: "memory");
    asm volatile("s_barrier" ::: "memory");  // tile t fully in LDS for all waves
    int bc = t % 3;
    const __hip_bfloat16* Ab = As + bc * 8192;
    const __hip_bfloat16* Bb = Bs + bc * 4096;
    // pinned issue order: af0..af3, bf0 | bf1 | bf2 | bf3
    short8 af0 = *(const short8*)&Ab[aoff[0]];
    short8 af1 = *(const short8*)&Ab[aoff[1]];
    short8 af2 = *(const short8*)&Ab[aoff[2]];
    short8 af3 = *(const short8*)&Ab[aoff[3]];
    short8 bf0 = *(const short8*)&Bb[boff[0]];
    __builtin_amdgcn_sched_barrier(0);
    short8 bf1 = *(const short8*)&Bb[boff[1]];
    __builtin_amdgcn_sched_barrier(0);
    short8 bf2 = *(const short8*)&Bb[boff[2]];
    __builtin_amdgcn_sched_barrier(0);
    short8 bf3 = *(const short8*)&Bb[boff[3]];
    __builtin_amdgcn_sched_barrier(0);
    asm volatile("s_waitcnt lgkmcnt(3)" ::: "memory");  // af0-3 + bf0 done
    __builtin_amdgcn_sched_barrier(0);
    __builtin_amdgcn_s_setprio(1);
    acc[0][0] = __builtin_amdgcn_mfma_f32_16x16x32_bf16(af0, bf0, acc[0][0], 0, 0, 0);
    acc[1][0] = __builtin_amdgcn_mfma_f32_16x16x32_bf16(af1, bf0, acc[1][0], 0, 0, 0);
    acc[2][0] = __builtin_amdgcn_mfma_f32_16x16x32_bf16(af2, bf0, acc[2][0], 0, 0, 0);
    acc[3][0] = __builtin_amdgcn_mfma_f32_16x16x32_bf16(af3, bf0, acc[3][0], 0, 0, 0);
    __builtin_amdgcn_s_setprio(0);
    asm volatile("s_waitcnt lgkmcnt(2)" ::: "memory");
    __builtin_amdgcn_sched_barrier(0);
    __builtin_amdgcn_s_setprio(1);
    acc[0][1] = __builtin_amdgcn_mfma_f32_16x16x32_bf16(af0, bf1, acc[0][1], 0, 0, 0);
    acc[1][1] = __builtin_amdgcn_mfma_f32_16x16x32_bf16(af1, bf1, acc[1][1], 0, 0, 0);
    acc[2][1] = __builtin_amdgcn_mfma_f32_16x16x32_bf16(af2, bf1, acc[2][1], 0, 0, 0);
    acc[3][1] = __builtin_amdgcn_mfma_f32_16x16x32_bf16(af3, bf1, acc[3][1], 0, 0, 0);
    __builtin_amdgcn_s_setprio(0);
    asm volatile("s_waitcnt lgkmcnt(1)" ::: "memory");
    __builtin_amdgcn_sched_barrier(0);
    __builtin_amdgcn_s_setprio(1);
    acc[0][2] = __builtin_amdgcn_mfma_f32_16x16x32_bf16(af0, bf2, acc[0][2], 0, 0, 0);
    acc[1][2] = __builtin_amdgcn_mfma_f32_16x16x32_bf16(af1, bf2, acc[1][2], 0, 0, 0);
    acc[2][2] = __builtin_amdgcn_mfma_f32_16x16x32_bf16(af2, bf2, acc[2][2], 0, 0, 0);
    acc[3][2] = __builtin_amdgcn_mfma_f32_16x16x32_bf16(af3, bf2, acc[3][2], 0, 0, 0);
    __builtin_amdgcn_s_setprio(0);
    asm volatile("s_waitcnt lgkmcnt(0)" ::: "memory");
    __builtin_amdgcn_sched_barrier(0);
    asm volatile("s_barrier" ::: "memory");  // all reads of buf t done -> restage ok
    __builtin_amdgcn_s_setprio(1);
    acc[0][3] = __builtin_amdgcn_mfma_f32_16x16x32_bf16(af0, bf3, acc[0][3], 0, 0, 0);
    acc[1][3] = __builtin_amdgcn_mfma_f32_16x16x32_bf16(af1, bf3, acc[1][3], 0, 0, 0);
    acc[2][3] = __builtin_amdgcn_mfma_f32_16x16x32_bf16(af2, bf3, acc[2][3], 0, 0, 0);
    acc[3][3] = __builtin_amdgcn_mfma_f32_16x16x32_bf16(af3, bf3, acc[3][3], 0, 0, 0);
    __builtin_amdgcn_s_setprio(0);
  }
}

// ---------------- GEMM1 + fused 7-tap conv epilogue: writes dwT directly ----------------
__global__ __launch_bounds__(512, 4) void k_gemm1(const __hip_bfloat16* __restrict__ xbT,
                                                  const __hip_bfloat16* __restrict__ w1b,
                                                  const float* __restrict__ b1,
                                                  const float* __restrict__ weff,
                                                  const float* __restrict__ beff,
                                                  __hip_bfloat16* __restrict__ dwT) {
  __shared__ __hip_bfloat16 As[3 * 256 * 32];
  __shared__ __hip_bfloat16 Bs[3 * 128 * 32];
  // 392 blocks; bijective XCD swizzle, o-tile fastest within XCD
  int swz = (blockIdx.x & 7) * 49 + (blockIdx.x >> 3);
  int rt = swz >> 2, ot = swz & 3;
  int n0 = rt * 256, o0 = ot * 128;
  f32x4 acc[4][4];
#pragma unroll
  for (int a = 0; a < 4; a++)
#pragma unroll
    for (int c = 0; c < 4; c++) acc[a][c] = (f32x4){0.f, 0.f, 0.f, 0.f};
  gemm_core<1024>(xbT + (size_t)n0 * CIN, w1b + (size_t)o0 * CIN, As, Bs, acc);

  int tid = threadIdx.x, lane = tid & 63, w = tid >> 6;
  int wm = w >> 1, wn = w & 1, ln = lane & 15, lm = lane >> 4;
  bool hiT = (lm & 1);
#pragma unroll
  for (int nf = 0; nf < 4; nf++) {
    int o = o0 + wn * 64 + nf * 16 + ln;
    float e[7];
#pragma unroll
    for (int u = 0; u < 7; u++) e[u] = weff[o * 8 + u];
    float be = beff[o];
    float bo = b1[o];
#pragma unroll
    for (int mf = 0; mf < 4; mf++) {
      float av[4], pv[4];
#pragma unroll
      for (int j = 0; j < 4; j++) av[j] = acc[mf][nf][j] + bo;
#pragma unroll
      for (int j = 0; j < 4; j++) pv[j] = __shfl_xor(av[j], 16, 64);
      float ov[4];
      if (hiT) {
#pragma unroll
        for (int j = 0; j < 4; j++) {
          float s = be;
#pragma unroll
          for (int u = 0; u < 7; u++) {
            int ss = 4 + j + u - 3;
            if (ss >= 0 && ss < 8) s += e[u] * (ss < 4 ? pv[ss] : av[ss - 4]);
          }
          ov[j] = s;
        }
      } else {
#pragma unroll
        for (int j = 0; j < 4; j++) {
          float s = be;
#pragma unroll
          for (int u = 0; u < 7; u++) {
            int ss = j + u - 3;
            if (ss >= 0 && ss < 8) s += e[u] * (ss < 4 ? av[ss] : pv[ss - 4]);
          }
          ov[j] = s;
        }
      }
      int grow = n0 + wm * 64 + mf * 16 + ((lm >> 1) & 1) * 8;  // group start row (mult of 8)
      int gidx = grow >> 3;                                      // = b*196 + hw
      int gb = gidx / HWS, ghw = gidx - gb * HWS;
      int tb = hiT ? 4 : 0;
#pragma unroll
      for (int j = 0; j < 4; j++) {
        size_t rr = (size_t)gb * NPB + (size_t)(tb + j) * HWS + ghw;
        dwT[rr * ICH + o] = __float2bfloat16(ov[j]);
      }
    }
  }
}

// ---------------- GEMM2: out = w2b . dwT + b2 + residual; LDS-bounced coalesced epilogue ----------------
__global__ __launch_bounds__(512, 4) void k_gemm2(const __hip_bfloat16* __restrict__ dwT,
                                                  const __hip_bfloat16* __restrict__ w2b,
                                                  const float* __restrict__ b2,
                                                  const float* __restrict__ xres,
                                                  float* __restrict__ out) {
  __shared__ __align__(16) char smem[73728];
  __hip_bfloat16* As = (__hip_bfloat16*)smem;            // 3*256*32 elems = 49152 B
  __hip_bfloat16* Bs = (__hip_bfloat16*)(smem + 49152);  // 3*128*32 elems = 24576 B
  // 784 blocks; bijective XCD swizzle, m-tile fastest within XCD
  int swz = (blockIdx.x & 7) * 98 + (blockIdx.x >> 3);
  int nt = swz >> 2, mt = swz & 3;
  int n0 = nt * 128, m0 = mt * 256;
  f32x4 acc[4][4];
#pragma unroll
  for (int a = 0; a < 4; a++)
#pragma unroll
    for (int c = 0; c < 4; c++) acc[a][c] = (f32x4){0.f, 0.f, 0.f, 0.f};
  gemm_core<512>(w2b + (size_t)m0 * ICH, dwT + (size_t)n0 * ICH, As, Bs, acc);

  int tid = threadIdx.x, lane = tid & 63, w = tid >> 6;
  int wm = w >> 1, wn = w & 1, ln = lane & 15, lm = lane >> 4;
  // epilogue: bounce acc through LDS as fp32 [o2l 128][col 132-pad], 2 passes over o2 halves
  float* arr = (float*)smem;
  int c = tid & 127;
  int o2r = tid >> 7;  // 0..3, wave-uniform
  int n2 = n0 + c;
  int bb = n2 / NPB, r = n2 - bb * NPB;
  int t2 = r / HWS, hw = r - t2 * HWS;
  size_t nbase = ((size_t)((bb * TT + t2) * CIN)) * HWS + hw;
#pragma unroll
  for (int pass = 0; pass < 2; pass++) {
    __syncthreads();
    if ((wm >> 1) == pass) {
#pragma unroll
      for (int mf = 0; mf < 4; mf++)
#pragma unroll
        for (int nf = 0; nf < 4; nf++)
#pragma unroll
          for (int j = 0; j < 4; j++) {
            int o2l = (wm & 1) * 64 + mf * 16 + lm * 4 + j;
            int col = wn * 64 + nf * 16 + ln;
            arr[o2l * 132 + col] = acc[mf][nf][j];
          }
    }
    __syncthreads();
    for (int it = 0; it < 32; it++) {
      int o2l = it * 4 + o2r;
      float v = arr[o2l * 132 + c];
      int o2 = m0 + pass * 128 + o2l;
      size_t a = nbase + (size_t)o2 * HWS;
      out[a] = v + b2[o2] + xres[a];
    }
  }
}

extern "C" void kernel_launch(void* const* d_in, const int* in_sizes, int n_in,
                              void* d_out, int out_size, void* d_ws, size_t ws_size,
                              hipStream_t stream) {
  const float* x   = (const float*)d_in[0];
  const float* w1  = (const float*)d_in[1];
  const float* b1  = (const float*)d_in[2];
  const float* wb1 = (const float*)d_in[3];
  const float* bb1 = (const float*)d_in[4];
  const float* wb2 = (const float*)d_in[5];
  const float* bb2 = (const float*)d_in[6];
  const float* wb3 = (const float*)d_in[7];
  const float* bb3 = (const float*)d_in[8];
  const float* wb4 = (const float*)d_in[9];
  const float* bb4 = (const float*)d_in[10];
  const float* w2  = (const float*)d_in[11];
  const float* b2  = (const float*)d_in[12];
  float* out = (float*)d_out;

  // d_out as scratch: xbT bf16 [NF][CIN] at offset 0 (51.4MB; dead before gemm2 writes out)
  __hip_bfloat16* xbT = (__hip_bfloat16*)d_out;

  // ws: dwT 25.69MB + w1b 1MB + w2b 1MB + weff 16KB + beff 2KB
  char* ws = (char*)d_ws;
  __hip_bfloat16* dwT = (__hip_bfloat16*)ws;
  __hip_bfloat16* w1b = (__hip_bfloat16*)(ws + 25690112);
  __hip_bfloat16* w2b = (__hip_bfloat16*)(ws + 25690112 + 1048576);
  float* weff = (float*)(ws + 25690112 + 2097152);
  float* beff = weff + 4096;

  k_prep<<<CB * TT * 16 * 4 + (CIN * ICH + 255) / 256, 256, 0, stream>>>(
      x, xbT, w1, w2, wb1, bb1, wb2, bb2, wb3, bb3, wb4, bb4, w1b, w2b, weff, beff);
  k_gemm1<<<392, 512, 0, stream>>>(xbT, w1b, b1, weff, beff, dwT);
  k_gemm2<<<784, 512, 0, stream>>>(dwT, w2b, b2, x, out);
}

// Round 8
// 126.120 us; speedup vs baseline: 1.7101x; 1.2299x over previous
//
#include <hip/hip_runtime.h>
#include <hip/hip_bf16.h>

typedef short short8 __attribute__((ext_vector_type(8)));
typedef float f32x4 __attribute__((ext_vector_type(4)));
typedef unsigned int uint;

#define CB   16
#define TT   8
#define CIN  1024
#define ICH  512
#define HWS  196
#define NPB  1568   // cols per batch (196*8)
#define NF   25088  // flat cols = 16*1568

static __device__ __forceinline__ unsigned short f2bf(float f) {
  __hip_bfloat16 h = __float2bfloat16(f); unsigned short u; __builtin_memcpy(&u, &h, 2); return u;
}

// async global->LDS, 16B per lane; LDS dest is wave-uniform base + lane*16
static __device__ __forceinline__ void stage16(const void* g, void* l) {
  __builtin_amdgcn_global_load_lds(
      (const __attribute__((address_space(1))) unsigned int*)(unsigned long long)g,
      (__attribute__((address_space(3))) unsigned int*)(unsigned int)(unsigned long long)l,
      16, 0, 0);
}

// ---------------- fused prep: x-transpose blocks [0,8192) + weight blocks ----------------
__global__ void k_prep(const float* __restrict__ x, __hip_bfloat16* __restrict__ xbT,
    const float* __restrict__ w1, const float* __restrict__ w2,
    const float* __restrict__ wb1, const float* __restrict__ bb1,
    const float* __restrict__ wb2, const float* __restrict__ bb2,
    const float* __restrict__ wb3, const float* __restrict__ bb3,
    const float* __restrict__ wb4, const float* __restrict__ bb4,
    __hip_bfloat16* __restrict__ w1b, __hip_bfloat16* __restrict__ w2b,
    float* __restrict__ weff, float* __restrict__ beff) {
  int bid = blockIdx.x;
  if (bid >= CB * TT * 16 * 4) {
    int idx = (bid - CB * TT * 16 * 4) * 256 + threadIdx.x;
    if (idx < CIN * ICH) {
      w1b[idx] = __float2bfloat16(w1[idx]);
      w2b[idx] = __float2bfloat16(w2[idx]);
    }
    if (idx < ICH) {
      float e[7];
#pragma unroll
      for (int u = 0; u < 7; u++) e[u] = wb4[idx * 7 + u];
#pragma unroll
      for (int u = 0; u < 5; u++) e[u + 1] += wb3[idx * 5 + u];
#pragma unroll
      for (int u = 0; u < 3; u++) e[u + 2] += wb2[idx * 3 + u];
      e[3] += wb1[idx];
#pragma unroll
      for (int u = 0; u < 7; u++) weff[idx * 8 + u] = e[u];
      weff[idx * 8 + 7] = 0.f;
      beff[idx] = bb1[idx] + bb2[idx] + bb3[idx] + bb4[idx];
    }
    return;
  }
  __shared__ float tile[64][51];
  int ht = bid & 3;
  int ct = (bid >> 2) & 15;
  int t  = (bid >> 6) & 7;
  int b  = bid >> 9;
  int c0 = ct * 64, h0 = ht * 49;
  const float* src = x + ((size_t)((b * TT + t) * CIN + c0)) * HWS + h0;
  for (int idx = threadIdx.x; idx < 64 * 49; idx += 256) {
    int r = idx / 49, q = idx - r * 49;
    tile[r][q] = src[(size_t)r * HWS + q];
  }
  __syncthreads();
  for (int idx = threadIdx.x; idx < 49 * 16; idx += 256) {
    int h = idx >> 4, g = idx & 15;
    ushort4 pk;
    pk.x = f2bf(tile[g * 4 + 0][h]);
    pk.y = f2bf(tile[g * 4 + 1][h]);
    pk.z = f2bf(tile[g * 4 + 2][h]);
    pk.w = f2bf(tile[g * 4 + 3][h]);
    size_t n1 = (size_t)(h0 + h) * TT + t;
    *(ushort4*)&xbT[((size_t)b * NPB + n1) * CIN + (c0 + g * 4)] = pk;
  }
}

// ---------------- 256x256 GEMM core, BK=64, 4 phases/K-tile, counted vmcnt ----------------
// 8 waves = 2m x 4n. Per-wave rows INTERLEAVED at 16 granularity:
//   A-fragment mf (0..7) -> rows mf*32 + wm*16 + ln, so fragments 0..3 lie in
//   A-half0 (rows 0..127) and 4..7 in A-half1 (rows 128..255) for EVERY wave.
//   This matches the drain schedule (the R7 race: wm-block mapping made wm=1
//   waves read Ah1 in phase 0 where only Ah0 was guaranteed).
// Stage order per iter (tile t+1): ph0 Bh0, ph1 Bh1, ph2 Ah0, ph3 Ah1 (2 loads each).
// FIFO waits: steady ph0 vmcnt(4) [drains Bh0,Bh1,Ah0 of t], ph2 vmcnt(6) [drains Ah1];
// last iter ph0 vmcnt(2), ph2 vmcnt(0). Barriers: ph0-mid, ph2-mid, ph3-end.
template <int KD>
static __device__ __forceinline__ void gemm_core64(
    const __hip_bfloat16* __restrict__ Ar,  // 256 rows x KD (k-contiguous)
    const __hip_bfloat16* __restrict__ Br,  // 256 rows x KD
    __hip_bfloat16* As, __hip_bfloat16* Bs, f32x4 (&acc)[8][4]) {
  constexpr int NT = KD / 64;
  const int tid = threadIdx.x;
  const int lane = tid & 63, w = tid >> 6;
  const int wm = w >> 2, wn = w & 3;
  const int ln = lane & 15, lm = lane >> 4;
  // staging: wave w, call q, half h -> rows h*128 + w*16 + q*8 + (lane>>3)
  const int srow = lane >> 3;                 // 0..7
  const int schk = (lane & 7) ^ srow;         // pre-swizzled source chunk
  const __hip_bfloat16* aS = Ar + (size_t)(w * 16 + srow) * KD + schk * 8;
  const __hip_bfloat16* bS = Br + (size_t)(w * 16 + srow) * KD + schk * 8;
  __hip_bfloat16* aD = As + (w * 16) * 64;
  __hip_bfloat16* bD = Bs + (w * 16) * 64;
  // read-side swizzled chunk offsets (row&7 == ln&7 for all fragment rows)
  const int ck0 = ((lm) ^ (ln & 7)) * 8;
  const int ck1 = ((4 + lm) ^ (ln & 7)) * 8;
  int ra[8], rb[4];
#pragma unroll
  for (int mf = 0; mf < 8; mf++) ra[mf] = (mf * 32 + wm * 16 + ln) * 64;
#pragma unroll
  for (int nf = 0; nf < 4; nf++) rb[nf] = (wn * 64 + nf * 16 + ln) * 64;

#define STG_(src, dst, h, q, kt, buf) \
  stage16(src + (size_t)((h) * 128 + (q) * 8) * KD + (kt) * 64, \
          dst + (buf) * 16384 + ((h) * 128 + (q) * 8) * 64)

  // prologue: tile 0 -> buf 0, order B0,B1,A0,A1
  STG_(bS, bD, 0, 0, 0, 0); STG_(bS, bD, 0, 1, 0, 0);
  STG_(bS, bD, 1, 0, 0, 0); STG_(bS, bD, 1, 1, 0, 0);
  STG_(aS, aD, 0, 0, 0, 0); STG_(aS, aD, 0, 1, 0, 0);
  STG_(aS, aD, 1, 0, 0, 0); STG_(aS, aD, 1, 1, 0, 0);

  short8 af[4], bfA[4], bfB[4];
  for (int t = 0; t < NT; t++) {
    const int buf = t & 1, nb = buf ^ 1;
    const bool has = (t + 1 < NT);
    const int bufo = buf * 16384;
    const __hip_bfloat16* Ab = As + bufo;
    const __hip_bfloat16* Bb = Bs + bufo;
    // ---- phase 0: kk0, frag 0..3 (A rows 0..127 = Ah0) ----
    if (has) { STG_(bS, bD, 0, 0, t + 1, nb); STG_(bS, bD, 0, 1, t + 1, nb); }
    if (has) asm volatile("s_waitcnt vmcnt(4)" ::: "memory");
    else     asm volatile("s_waitcnt vmcnt(2)" ::: "memory");
    asm volatile("s_barrier" ::: "memory");
#pragma unroll
    for (int q = 0; q < 4; q++) af[q] = *(const short8*)&Ab[ra[q] + ck0];
#pragma unroll
    for (int nf = 0; nf < 4; nf++) bfA[nf] = *(const short8*)&Bb[rb[nf] + ck0];
    asm volatile("s_waitcnt lgkmcnt(0)" ::: "memory");
    __builtin_amdgcn_sched_barrier(0);
    __builtin_amdgcn_s_setprio(1);
#pragma unroll
    for (int nf = 0; nf < 4; nf++)
#pragma unroll
      for (int q = 0; q < 4; q++)
        acc[q][nf] = __builtin_amdgcn_mfma_f32_16x16x32_bf16(af[q], bfA[nf], acc[q][nf], 0, 0, 0);
    __builtin_amdgcn_s_setprio(0);
    // ---- phase 1: kk1, frag 0..3 ----
    if (has) { STG_(bS, bD, 1, 0, t + 1, nb); STG_(bS, bD, 1, 1, t + 1, nb); }
#pragma unroll
    for (int q = 0; q < 4; q++) af[q] = *(const short8*)&Ab[ra[q] + ck1];
#pragma unroll
    for (int nf = 0; nf < 4; nf++) bfB[nf] = *(const short8*)&Bb[rb[nf] + ck1];
    asm volatile("s_waitcnt lgkmcnt(0)" ::: "memory");
    __builtin_amdgcn_sched_barrier(0);
    __builtin_amdgcn_s_setprio(1);
#pragma unroll
    for (int nf = 0; nf < 4; nf++)
#pragma unroll
      for (int q = 0; q < 4; q++)
        acc[q][nf] = __builtin_amdgcn_mfma_f32_16x16x32_bf16(af[q], bfB[nf], acc[q][nf], 0, 0, 0);
    __builtin_amdgcn_s_setprio(0);
    // ---- phase 2: kk0, frag 4..7 (A rows 128..255 = Ah1) ----
    if (has) { STG_(aS, aD, 0, 0, t + 1, nb); STG_(aS, aD, 0, 1, t + 1, nb); }
    if (has) asm volatile("s_waitcnt vmcnt(6)" ::: "memory");
    else     asm volatile("s_waitcnt vmcnt(0)" ::: "memory");
    asm volatile("s_barrier" ::: "memory");
#pragma unroll
    for (int q = 0; q < 4; q++) af[q] = *(const short8*)&Ab[ra[4 + q] + ck0];
    asm volatile("s_waitcnt lgkmcnt(0)" ::: "memory");
    __builtin_amdgcn_sched_barrier(0);
    __builtin_amdgcn_s_setprio(1);
#pragma unroll
    for (int nf = 0; nf < 4; nf++)
#pragma unroll
      for (int q = 0; q < 4; q++)
        acc[4 + q][nf] = __builtin_amdgcn_mfma_f32_16x16x32_bf16(af[q], bfA[nf], acc[4 + q][nf], 0, 0, 0);
    __builtin_amdgcn_s_setprio(0);
    // ---- phase 3: kk1, frag 4..7 ----
    if (has) { STG_(aS, aD, 1, 0, t + 1, nb); STG_(aS, aD, 1, 1, t + 1, nb); }
#pragma unroll
    for (int q = 0; q < 4; q++) af[q] = *(const short8*)&Ab[ra[4 + q] + ck1];
    asm volatile("s_waitcnt lgkmcnt(0)" ::: "memory");
    __builtin_amdgcn_sched_barrier(0);
    __builtin_amdgcn_s_setprio(1);
#pragma unroll
    for (int nf = 0; nf < 4; nf++)
#pragma unroll
      for (int q = 0; q < 4; q++)
        acc[4 + q][nf] = __builtin_amdgcn_mfma_f32_16x16x32_bf16(af[q], bfB[nf], acc[4 + q][nf], 0, 0, 0);
    __builtin_amdgcn_s_setprio(0);
    asm volatile("s_barrier" ::: "memory");  // all reads of buf done -> restage safe
  }
#undef STG_
}

// ---------------- GEMM1 + fused 7-tap conv epilogue: writes dwT directly ----------------
__global__ __launch_bounds__(512, 2) void k_gemm1(const __hip_bfloat16* __restrict__ xbT,
                                                  const __hip_bfloat16* __restrict__ w1b,
                                                  const float* __restrict__ b1,
                                                  const float* __restrict__ weff,
                                                  const float* __restrict__ beff,
                                                  __hip_bfloat16* __restrict__ dwT) {
  __shared__ __hip_bfloat16 As[2 * 256 * 64];
  __shared__ __hip_bfloat16 Bs[2 * 256 * 64];
  // bijective XCD swizzle for nwg=196 (q=24, r=4): o-tile fastest within XCD
  int xcd = blockIdx.x & 7, i = blockIdx.x >> 3;
  int id = (xcd < 4 ? xcd * 25 : 100 + (xcd - 4) * 24) + i;
  int rt = id >> 1, ot = id & 1;
  int n0 = rt * 256, o0 = ot * 256;
  f32x4 acc[8][4];
#pragma unroll
  for (int a = 0; a < 8; a++)
#pragma unroll
    for (int c = 0; c < 4; c++) acc[a][c] = (f32x4){0.f, 0.f, 0.f, 0.f};
  gemm_core64<1024>(xbT + (size_t)n0 * CIN, w1b + (size_t)o0 * CIN, As, Bs, acc);

  int tid = threadIdx.x, lane = tid & 63, w = tid >> 6;
  int wm = w >> 2, wn = w & 3, ln = lane & 15, lm = lane >> 4;
  bool hiT = (lm & 1);
#pragma unroll
  for (int nf = 0; nf < 4; nf++) {
    int o = o0 + wn * 64 + nf * 16 + ln;
    float e[7];
#pragma unroll
    for (int u = 0; u < 7; u++) e[u] = weff[o * 8 + u];
    float be = beff[o];
    float bo = b1[o];
#pragma unroll
    for (int mf = 0; mf < 8; mf++) {
      float av[4], pv[4];
#pragma unroll
      for (int j = 0; j < 4; j++) av[j] = acc[mf][nf][j] + bo;
#pragma unroll
      for (int j = 0; j < 4; j++) pv[j] = __shfl_xor(av[j], 16, 64);
      float ov[4];
      if (hiT) {
#pragma unroll
        for (int j = 0; j < 4; j++) {
          float s = be;
#pragma unroll
          for (int u = 0; u < 7; u++) {
            int ss = 4 + j + u - 3;
            if (ss >= 0 && ss < 8) s += e[u] * (ss < 4 ? pv[ss] : av[ss - 4]);
          }
          ov[j] = s;
        }
      } else {
#pragma unroll
        for (int j = 0; j < 4; j++) {
          float s = be;
#pragma unroll
          for (int u = 0; u < 7; u++) {
            int ss = j + u - 3;
            if (ss >= 0 && ss < 8) s += e[u] * (ss < 4 ? av[ss] : pv[ss - 4]);
          }
          ov[j] = s;
        }
      }
      // row = n0 + mf*32 + wm*16 + lm*4 + j; group start (mult of 8):
      int grow = n0 + mf * 32 + wm * 16 + ((lm >> 1) & 1) * 8;
      int gidx = grow >> 3;  // = b*196 + hw
      int gb = gidx / HWS, ghw = gidx - gb * HWS;
      int tb = hiT ? 4 : 0;
#pragma unroll
      for (int j = 0; j < 4; j++) {
        size_t rr = (size_t)gb * NPB + (size_t)(tb + j) * HWS + ghw;
        dwT[rr * ICH + o] = __float2bfloat16(ov[j]);
      }
    }
  }
}

// ---------------- GEMM2: out = w2b . dwT + b2 + residual; bounced float4 epilogue ----------------
__global__ __launch_bounds__(512, 2) void k_gemm2(const __hip_bfloat16* __restrict__ dwT,
                                                  const __hip_bfloat16* __restrict__ w2b,
                                                  const float* __restrict__ b2,
                                                  const float* __restrict__ xres,
                                                  float* __restrict__ out) {
  __shared__ __align__(16) char smem[131072];
  __hip_bfloat16* As = (__hip_bfloat16*)smem;
  __hip_bfloat16* Bs = (__hip_bfloat16*)(smem + 65536);
  // 392 blocks = 8 x 49; m-tile fastest within XCD (shares dwT n-panel)
  int id = (blockIdx.x & 7) * 49 + (blockIdx.x >> 3);
  int nt = id >> 2, mt = id & 3;
  int n0 = nt * 256, m0 = mt * 256;
  f32x4 acc[8][4];
#pragma unroll
  for (int a = 0; a < 8; a++)
#pragma unroll
    for (int c = 0; c < 4; c++) acc[a][c] = (f32x4){0.f, 0.f, 0.f, 0.f};
  gemm_core64<512>(w2b + (size_t)m0 * ICH, dwT + (size_t)n0 * ICH, As, Bs, acc);

  int tid = threadIdx.x, lane = tid & 63, w = tid >> 6;
  int wm = w >> 2, wn = w & 3, ln = lane & 15, lm = lane >> 4;
  float* arr = (float*)smem;  // bounce: [64 o2-rows][260 cols] fp32 per pass
  // reader decode: lane's 4 cols (NPB,HWS multiples of 4 -> hw<=192 always, float4 safe)
  int fc = tid & 63, fr = tid >> 6;  // fr wave-uniform
  int n2 = n0 + fc * 4;
  int bb = n2 / NPB, r = n2 - bb * NPB;
  int t2 = r / HWS, hw = r - t2 * HWS;
  size_t base4 = ((size_t)((bb * TT + t2) * CIN)) * HWS + hw;
#pragma unroll
  for (int p = 0; p < 4; p++) {
    __syncthreads();
    // o2 row = m0 + mf*32 + wm*16 + lm*4 + j; pass p covers mf = 2p, 2p+1
#pragma unroll
    for (int q2 = 0; q2 < 2; q2++) {
      int mf = p * 2 + q2;
#pragma unroll
      for (int nf = 0; nf < 4; nf++)
#pragma unroll
        for (int j = 0; j < 4; j++)
          arr[(q2 * 32 + wm * 16 + lm * 4 + j) * 260 + wn * 64 + nf * 16 + ln] = acc[mf][nf][j];
    }
    __syncthreads();
#pragma unroll
    for (int it = 0; it < 8; it++) {
      int o2l = it * 8 + fr;
      f32x4 v = *(const f32x4*)&arr[o2l * 260 + fc * 4];
      int o2 = m0 + p * 64 + o2l;
      float bo = b2[o2];
      size_t a = base4 + (size_t)o2 * HWS;
      float4 xr = *(const float4*)(xres + a);
      float4 ov = make_float4(v[0] + bo + xr.x, v[1] + bo + xr.y,
                              v[2] + bo + xr.z, v[3] + bo + xr.w);
      *(float4*)(out + a) = ov;
    }
  }
}

extern "C" void kernel_launch(void* const* d_in, const int* in_sizes, int n_in,
                              void* d_out, int out_size, void* d_ws, size_t ws_size,
                              hipStream_t stream) {
  const float* x   = (const float*)d_in[0];
  const float* w1  = (const float*)d_in[1];
  const float* b1  = (const float*)d_in[2];
  const float* wb1 = (const float*)d_in[3];
  const float* bb1 = (const float*)d_in[4];
  const float* wb2 = (const float*)d_in[5];
  const float* bb2 = (const float*)d_in[6];
  const float* wb3 = (const float*)d_in[7];
  const float* bb3 = (const float*)d_in[8];
  const float* wb4 = (const float*)d_in[9];
  const float* bb4 = (const float*)d_in[10];
  const float* w2  = (const float*)d_in[11];
  const float* b2  = (const float*)d_in[12];
  float* out = (float*)d_out;

  // d_out as scratch: xbT bf16 [NF][CIN] at offset 0 (51.4MB; dead before gemm2 writes out)
  __hip_bfloat16* xbT = (__hip_bfloat16*)d_out;

  // ws: dwT 25.69MB + w1b 1MB + w2b 1MB + weff 16KB + beff 2KB
  char* ws = (char*)d_ws;
  __hip_bfloat16* dwT = (__hip_bfloat16*)ws;
  __hip_bfloat16* w1b = (__hip_bfloat16*)(ws + 25690112);
  __hip_bfloat16* w2b = (__hip_bfloat16*)(ws + 25690112 + 1048576);
  float* weff = (float*)(ws + 25690112 + 2097152);
  float* beff = weff + 4096;

  k_prep<<<CB * TT * 16 * 4 + (CIN * ICH + 255) / 256, 256, 0, stream>>>(
      x, xbT, w1, w2, wb1, bb1, wb2, bb2, wb3, bb3, wb4, bb4, w1b, w2b, weff, beff);
  k_gemm1<<<196, 512, 0, stream>>>(xbT, w1b, b1, weff, beff, dwT);
  k_gemm2<<<392, 512, 0, stream>>>(dwT, w2b, b2, x, out);
}